// Round 13
// baseline (191.992 us; speedup 1.0000x reference)
//
#include <hip/hip_runtime.h>

#define D_MODEL 1024
#define NHEAD 16
#define DKH 64
#define BATCH 4
#define SEQ 2048
#define MROWS (BATCH*SEQ)   // 8192

typedef unsigned short u16;
typedef __attribute__((ext_vector_type(8))) short bf16x8;
typedef __attribute__((ext_vector_type(4))) float f32x4;

__device__ __forceinline__ u16 f2bf(float f) {
  union { float f; unsigned int u; } x; x.f = f;
  unsigned int r = x.u + 0x7FFFu + ((x.u >> 16) & 1u);
  return (u16)(r >> 16);
}
__device__ __forceinline__ u16 f2bf_fast(float f) {
  union { float f; unsigned int u; } x; x.f = f;
  return (u16)((x.u + 0x7FFFu) >> 16);
}

__device__ __forceinline__ f32x4 mfma16(bf16x8 a, bf16x8 b, f32x4 c) {
  return __builtin_amdgcn_mfma_f32_16x16x32_bf16(a, b, c, 0, 0, 0);
}

__device__ __forceinline__ void gld_lds16(const void* g, void* l) {
  __builtin_amdgcn_global_load_lds((const __attribute__((address_space(1))) unsigned int*)g,
                                   (__attribute__((address_space(3))) unsigned int*)l, 16, 0, 0);
}

// ---------------- W (1024x1024 f32) -> Wt bf16 transposed, 4 in one dispatch ----------------
__global__ __launch_bounds__(256) void transpose_cvt4(
    const float* __restrict__ W0, const float* __restrict__ W1,
    const float* __restrict__ W2, const float* __restrict__ W3,
    u16* __restrict__ T0, u16* __restrict__ T1,
    u16* __restrict__ T2, u16* __restrict__ T3) {
  const int z = blockIdx.z;
  const float* W = (z == 0) ? W0 : (z == 1) ? W1 : (z == 2) ? W2 : W3;
  u16* Wt = (z == 0) ? T0 : (z == 1) ? T1 : (z == 2) ? T2 : T3;
  __shared__ float tile[32][33];
  int bx = blockIdx.x * 32, by = blockIdx.y * 32;
  int tx = threadIdx.x, ty = threadIdx.y;
#pragma unroll
  for (int j = 0; j < 32; j += 8)
    tile[ty + j][tx] = W[(size_t)(by + ty + j) * D_MODEL + bx + tx];
  __syncthreads();
#pragma unroll
  for (int j = 0; j < 32; j += 8)
    Wt[(size_t)(bx + ty + j) * D_MODEL + by + tx] = f2bf(tile[tx][ty + j]);
}

// =====================================================================
// Pipelined 128x128 GEMM, BK=64, 4 waves — fused fp32 A, v2.
// A: fp32 global -> regs, DISTANCE-2 prefetch (two static sets a0r/a1r),
//    cvt_pk pack -> ds_write at P2-START (off the drain-barrier window).
// B: bf16 via global_load_lds (proven path).
// vmcnt ledger (issue order at tile t: ... B(t+1)@t-1P2, A(t+2)@tP1, B(t+2)@tP2):
//   P2-start: vmcnt(12) drains A(t+1) only  [t=14: vmcnt(4); t=15: skip]
//   P2-end:   vmcnt(12) drains B(t+1), keeps A(t+2)+B(t+2) in flight
//             [t=14: vmcnt(0)]; lgkmcnt(0) for the A ds_writes; barrier.
// =====================================================================
template <typename Epi>
__device__ __forceinline__ void gemm_pipe_f32a(const float* __restrict__ Ap32,
                                               const u16* __restrict__ Bp,
                                               int m0, int n0g, Epi epi) {
  __shared__ u16 As[2][128 * 64];
  __shared__ u16 Bs[2][128 * 64];
  const int tid = threadIdx.x;
  const int lane = tid & 63;
  const int w = tid >> 6;
  const int wm = w >> 1, wn = w & 1;
  const int lo = lane & 15, g = lane >> 4;
  const int swz = (lo & 7) << 4;
  const int sg = (tid & 7) ^ ((tid >> 3) & 7);
  const int srow = tid >> 3;  // 0..31

  f32x4 acc[4][4] = {};
  float4 a0r[8], a1r[8];  // set0 holds A(even tiles), set1 A(odd tiles)

  auto LOAD_A0 = [&](int tt) {
#pragma unroll
    for (int j = 0; j < 4; ++j) {
      const float* p = Ap32 + (size_t)(m0 + j * 32 + srow) * D_MODEL + tt * 64 + sg * 8;
      a0r[2 * j] = *(const float4*)p;
      a0r[2 * j + 1] = *(const float4*)(p + 4);
    }
  };
  auto LOAD_A1 = [&](int tt) {
#pragma unroll
    for (int j = 0; j < 4; ++j) {
      const float* p = Ap32 + (size_t)(m0 + j * 32 + srow) * D_MODEL + tt * 64 + sg * 8;
      a1r[2 * j] = *(const float4*)p;
      a1r[2 * j + 1] = *(const float4*)(p + 4);
    }
  };
  auto PACK8 = [&](const float4& u, const float4& v) {
    unsigned int p0, p1, p2, p3;
    asm("v_cvt_pk_bf16_f32 %0, %1, %2" : "=v"(p0) : "v"(u.x), "v"(u.y));
    asm("v_cvt_pk_bf16_f32 %0, %1, %2" : "=v"(p1) : "v"(u.z), "v"(u.w));
    asm("v_cvt_pk_bf16_f32 %0, %1, %2" : "=v"(p2) : "v"(v.x), "v"(v.y));
    asm("v_cvt_pk_bf16_f32 %0, %1, %2" : "=v"(p3) : "v"(v.z), "v"(v.w));
    union { unsigned int q[4]; bf16x8 v8; } r;
    r.q[0] = p0; r.q[1] = p1; r.q[2] = p2; r.q[3] = p3;
    return r.v8;
  };
  auto WRITE_A0 = [&](int buf) {
#pragma unroll
    for (int j = 0; j < 4; ++j)
      *(bf16x8*)&As[buf][j * 2048 + tid * 8] = PACK8(a0r[2 * j], a0r[2 * j + 1]);
  };
  auto WRITE_A1 = [&](int buf) {
#pragma unroll
    for (int j = 0; j < 4; ++j)
      *(bf16x8*)&As[buf][j * 2048 + tid * 8] = PACK8(a1r[2 * j], a1r[2 * j + 1]);
  };
  auto STAGE_B = [&](int buf, int tt) {
#pragma unroll
    for (int j = 0; j < 4; ++j)
      gld_lds16(Bp + (size_t)(n0g + j * 32 + srow) * D_MODEL + tt * 64 + sg * 8,
                &Bs[buf][j * 2048 + tid * 8]);
  };

  // prologue: A(0)[8] A(1)[8] B(0)[4] B(1)[4] = 24 outstanding
  LOAD_A0(0);
  LOAD_A1(1);
  STAGE_B(0, 0);
  STAGE_B(1, 1);
  asm volatile("s_waitcnt vmcnt(16)" ::: "memory");  // A(0) regs ready
  WRITE_A0(0);
  asm volatile("s_waitcnt vmcnt(4)" ::: "memory");   // B(0) in LDS; B(1) flies
  asm volatile("s_waitcnt lgkmcnt(0)" ::: "memory");
  __builtin_amdgcn_s_barrier();

#pragma unroll 1
  for (int t = 0; t < 16; ++t) {
    const int cur = t & 1;
    const int nb = cur ^ 1;
    const char* ab = (const char*)&As[cur][0];
    const char* bb2 = (const char*)&Bs[cur][0];

    // ---- P1: read B-frags + A-frags(m=0,1); issue A(t+2) reg loads ----
    bf16x8 bf[4][2], af[2][2];
#pragma unroll
    for (int n = 0; n < 4; ++n) {
      int row = wn * 64 + n * 16 + lo;
      bf[n][0] = *(const bf16x8*)(bb2 + row * 128 + ((g * 16) ^ swz));
      bf[n][1] = *(const bf16x8*)(bb2 + row * 128 + ((64 + g * 16) ^ swz));
    }
#pragma unroll
    for (int m = 0; m < 2; ++m) {
      int row = wm * 64 + m * 16 + lo;
      af[m][0] = *(const bf16x8*)(ab + row * 128 + ((g * 16) ^ swz));
      af[m][1] = *(const bf16x8*)(ab + row * 128 + ((64 + g * 16) ^ swz));
    }
    if (t + 2 < 16) {
      if (t & 1) LOAD_A1(t + 2); else LOAD_A0(t + 2);  // set (t&1) == parity of t+2
    }
    __builtin_amdgcn_s_barrier();
    __builtin_amdgcn_s_setprio(1);
#pragma unroll
    for (int s2 = 0; s2 < 2; ++s2)
#pragma unroll
      for (int m = 0; m < 2; ++m)
#pragma unroll
        for (int n = 0; n < 4; ++n)
          acc[m][n] = mfma16(af[m][s2], bf[n][s2], acc[m][n]);
    __builtin_amdgcn_s_setprio(0);
    __builtin_amdgcn_s_barrier();

    // ---- P2: drain A(t+1) regs, cvt+write to As[nb]; read af2; stage B(t+2) ----
    if (t + 1 < 16) {
      if (t + 2 < 16) asm volatile("s_waitcnt vmcnt(12)" ::: "memory");
      else            asm volatile("s_waitcnt vmcnt(4)" ::: "memory");
      if (t & 1) WRITE_A0(nb); else WRITE_A1(nb);      // A(t+1) lives in set nb
    }
    bf16x8 af2[2][2];
#pragma unroll
    for (int m = 0; m < 2; ++m) {
      int row = wm * 64 + (m + 2) * 16 + lo;
      af2[m][0] = *(const bf16x8*)(ab + row * 128 + ((g * 16) ^ swz));
      af2[m][1] = *(const bf16x8*)(ab + row * 128 + ((64 + g * 16) ^ swz));
    }
    if (t + 2 < 16) STAGE_B(cur, t + 2);
    __builtin_amdgcn_s_barrier();
    __builtin_amdgcn_s_setprio(1);
#pragma unroll
    for (int s2 = 0; s2 < 2; ++s2)
#pragma unroll
      for (int m = 0; m < 2; ++m)
#pragma unroll
        for (int n = 0; n < 4; ++n)
          acc[m + 2][n] = mfma16(af2[m][s2], bf[n][s2], acc[m + 2][n]);
    __builtin_amdgcn_s_setprio(0);
    if (t + 1 < 16) {
      // drain B(t+1); keep A(t+2)[8]+B(t+2)[4] in flight
      if (t + 2 < 16) asm volatile("s_waitcnt vmcnt(12)" ::: "memory");
      else            asm volatile("s_waitcnt vmcnt(0)" ::: "memory");
      asm volatile("s_waitcnt lgkmcnt(0)" ::: "memory");
      __builtin_amdgcn_s_barrier();
    }
  }

  epi(acc, wm, wn, lo, g);
}

// =====================================================================
// Pipelined 128x128 GEMM core, all-bf16 (EXACT R8 structure) — for O GEMM.
// =====================================================================
template <typename Epi>
__device__ __forceinline__ void gemm_pipe(const u16* __restrict__ Ap,
                                          const u16* __restrict__ Bp,
                                          int m0, int n0g, Epi epi) {
  __shared__ u16 As[2][128 * 64];
  __shared__ u16 Bs[2][128 * 64];
  const int tid = threadIdx.x;
  const int lane = tid & 63;
  const int w = tid >> 6;
  const int wm = w >> 1, wn = w & 1;
  const int lo = lane & 15, g = lane >> 4;
  const int swz = (lo & 7) << 4;
  const int sg = (tid & 7) ^ ((tid >> 3) & 7);
  const int srow = tid >> 3;  // 0..31

  f32x4 acc[4][4] = {};

  auto STAGE_A = [&](int buf, int tt, int j) {
    int row = j * 32 + srow;
    gld_lds16(Ap + (size_t)(m0 + row) * D_MODEL + tt * 64 + sg * 8,
              &As[buf][j * 2048 + tid * 8]);
  };
  auto STAGE_B = [&](int buf, int tt, int j) {
    int row = j * 32 + srow;
    gld_lds16(Bp + (size_t)(n0g + row) * D_MODEL + tt * 64 + sg * 8,
              &Bs[buf][j * 2048 + tid * 8]);
  };

  STAGE_A(0, 0, 0); STAGE_A(0, 0, 1); STAGE_A(0, 0, 2); STAGE_A(0, 0, 3);
  STAGE_B(0, 0, 0); STAGE_B(0, 0, 1); STAGE_B(0, 0, 2); STAGE_B(0, 0, 3);
  STAGE_B(1, 1, 0); STAGE_B(1, 1, 1); STAGE_B(1, 1, 2); STAGE_B(1, 1, 3);
  asm volatile("s_waitcnt vmcnt(4)" ::: "memory");
  __builtin_amdgcn_s_barrier();

  int cur = 0;
#pragma unroll 1
  for (int t = 0; t < 16; ++t) {
    const int nb = cur ^ 1;
    const char* ab = (const char*)&As[cur][0];
    const char* bb2 = (const char*)&Bs[cur][0];

    bf16x8 bf[4][2], af[2][2];
#pragma unroll
    for (int n = 0; n < 4; ++n) {
      int row = wn * 64 + n * 16 + lo;
      bf[n][0] = *(const bf16x8*)(bb2 + row * 128 + ((g * 16) ^ swz));
      bf[n][1] = *(const bf16x8*)(bb2 + row * 128 + ((64 + g * 16) ^ swz));
    }
#pragma unroll
    for (int m = 0; m < 2; ++m) {
      int row = wm * 64 + m * 16 + lo;
      af[m][0] = *(const bf16x8*)(ab + row * 128 + ((g * 16) ^ swz));
      af[m][1] = *(const bf16x8*)(ab + row * 128 + ((64 + g * 16) ^ swz));
    }
    if (t + 1 < 16) {
      STAGE_A(nb, t + 1, 0); STAGE_A(nb, t + 1, 1);
      STAGE_A(nb, t + 1, 2); STAGE_A(nb, t + 1, 3);
    }
    __builtin_amdgcn_s_barrier();
    __builtin_amdgcn_s_setprio(1);
#pragma unroll
    for (int s2 = 0; s2 < 2; ++s2)
#pragma unroll
      for (int m = 0; m < 2; ++m)
#pragma unroll
        for (int n = 0; n < 4; ++n)
          acc[m][n] = mfma16(af[m][s2], bf[n][s2], acc[m][n]);
    __builtin_amdgcn_s_setprio(0);
    __builtin_amdgcn_s_barrier();

    bf16x8 af2[2][2];
#pragma unroll
    for (int m = 0; m < 2; ++m) {
      int row = wm * 64 + (m + 2) * 16 + lo;
      af2[m][0] = *(const bf16x8*)(ab + row * 128 + ((g * 16) ^ swz));
      af2[m][1] = *(const bf16x8*)(ab + row * 128 + ((64 + g * 16) ^ swz));
    }
    if (t + 2 < 16) {
      STAGE_B(cur, t + 2, 0); STAGE_B(cur, t + 2, 1);
      STAGE_B(cur, t + 2, 2); STAGE_B(cur, t + 2, 3);
    }
    __builtin_amdgcn_s_barrier();
    __builtin_amdgcn_s_setprio(1);
#pragma unroll
    for (int s2 = 0; s2 < 2; ++s2)
#pragma unroll
      for (int m = 0; m < 2; ++m)
#pragma unroll
        for (int n = 0; n < 4; ++n)
          acc[m + 2][n] = mfma16(af2[m][s2], bf[n][s2], acc[m + 2][n]);
    __builtin_amdgcn_s_setprio(0);
    if (t + 2 < 16) asm volatile("s_waitcnt vmcnt(4)" ::: "memory");
    else            asm volatile("s_waitcnt vmcnt(0)" ::: "memory");
    __builtin_amdgcn_s_barrier();
    cur = nb;
  }

  epi(acc, wm, wn, lo, g);
}

// ---------------- fused QKV GEMM: fp32 A in, bf16 head-split out ----------------
__global__ __launch_bounds__(256, 2) void gemm_qkv_kernel(
    const float* __restrict__ Aq, const float* __restrict__ Ak, const float* __restrict__ Av,
    const u16* __restrict__ Wt,   // [3072][1024]
    const float* __restrict__ bq, const float* __restrict__ bk, const float* __restrict__ bv,
    u16* __restrict__ Qhd, u16* __restrict__ Khd, u16* __restrict__ Vhd, float qscale) {
  const int flat = blockIdx.x;
  const int swzb = (flat & 7) * 192 + (flat >> 3);
  const int m0 = (swzb / 24) * 128;
  const int n0g = (swzb % 24) * 128;
  const int chunk = n0g >> 10;  // block-uniform
  const float* Ap = (chunk == 0) ? Aq : (chunk == 1) ? Ak : Av;
  const float* bias = (chunk == 0) ? bq : (chunk == 1) ? bk : bv;
  const float scale = (chunk == 0) ? qscale : 1.0f;

  gemm_pipe_f32a(Ap, Wt, m0, n0g,
    [&](f32x4 (&acc)[4][4], int wm, int wn, int lo, int g) {
#pragma unroll
      for (int m = 0; m < 4; ++m)
#pragma unroll
        for (int n = 0; n < 4; ++n) {
          int row0 = m0 + wm * 64 + m * 16 + g * 4;
          int colc = (n0g & 1023) + wn * 64 + n * 16 + lo;
          int hh = colc >> 6, d = colc & 63;
          int bb = row0 >> 11;
          float v0 = (acc[m][n][0] + bias[colc]) * scale;
          float v1 = (acc[m][n][1] + bias[colc]) * scale;
          float v2 = (acc[m][n][2] + bias[colc]) * scale;
          float v3 = (acc[m][n][3] + bias[colc]) * scale;
          if (chunk < 2) {
            u16* out = chunk ? Khd : Qhd;
#pragma unroll
            for (int i = 0; i < 4; ++i) {
              int l = (row0 + i) & 2047;
              float vi = (i == 0) ? v0 : (i == 1) ? v1 : (i == 2) ? v2 : v3;
              out[(((size_t)(bb * NHEAD + hh)) * SEQ + l) * DKH + d] = f2bf(vi);
            }
          } else {
            // V: transposed per head [B][H][64][SEQ], keys sigma-permuted within 32
            int l = row0 & 2047;
            int kh = (l >> 2) & 7;
            int pos = (l & ~31) | ((2 * (kh & 3) + (kh >> 2)) << 2);
            ushort4 o;
            o.x = f2bf(v0); o.y = f2bf(v1); o.z = f2bf(v2); o.w = f2bf(v3);
            *(ushort4*)&Vhd[(((size_t)(bb * NHEAD + hh)) * DKH + d) * SEQ + pos] = o;
          }
        }
    });
}

// ---------------- O GEMM: fp32 out ----------------
__global__ __launch_bounds__(256, 2) void gemm_o_kernel(
    const u16* __restrict__ A, const u16* __restrict__ Bt,
    const float* __restrict__ bias, float* __restrict__ Cout) {
  const int flat = blockIdx.x;           // 512 blocks
  const int swzb = (flat & 7) * 64 + (flat >> 3);
  const int m0 = (swzb >> 3) * 128;
  const int n0g = (swzb & 7) * 128;

  gemm_pipe(A, Bt, m0, n0g,
    [&](f32x4 (&acc)[4][4], int wm, int wn, int lo, int g) {
#pragma unroll
      for (int m = 0; m < 4; ++m)
#pragma unroll
        for (int n = 0; n < 4; ++n) {
          int row0 = m0 + wm * 64 + m * 16 + g * 4;
          int col = n0g + wn * 64 + n * 16 + lo;
          float bcol = bias[col];
#pragma unroll
          for (int i = 0; i < 4; ++i)
            Cout[(size_t)(row0 + i) * D_MODEL + col] = acc[m][n][i] + bcol;
        }
    });
}

// ---------------- causal flash attention (EXACT R11, replay-safe) ----------------
__global__ __launch_bounds__(256, 3) void attn_kernel(
    const u16* __restrict__ Qh, const u16* __restrict__ Kh,
    const u16* __restrict__ Vt, u16* __restrict__ ctx) {
  const int blk = blockIdx.x;             // 1024 blocks
  const int xcd = blk & 7;
  const int local = blk >> 3;             // 0..127
  const int qb = 15 - (local >> 3);       // LPT: biggest q-blocks first
  const int head = xcd * 8 + (local & 7); // head-XCD affinity
  const int b = head >> 4, h = head & (NHEAD - 1);

  const int tid = threadIdx.x;
  const int lane = tid & 63;
  const int w = tid >> 6;                 // 0..3
  const int lo = lane & 15, g = lane >> 4;
  const int swz = (lo & 7) << 4;

  __shared__ u16 Ks[3][64 * 64];
  __shared__ u16 Vs[3][64 * 64];

  const size_t hoff = ((size_t)(b * NHEAD + h)) * SEQ * DKH;
  const u16* Qp = Qh + hoff;
  const u16* Kp = Kh + hoff;
  const u16* Vp = Vt + hoff;       // [64][SEQ]

  const int nt = 2 * qb + 2;
  const int qmin = qb * 128 + w * 32;

  bf16x8 aq[2][2];
#pragma unroll
  for (int qs = 0; qs < 2; ++qs)
#pragma unroll
    for (int cc = 0; cc < 2; ++cc)
      aq[qs][cc] = *(const bf16x8*)(Qp + (size_t)(qmin + qs * 16 + lo) * DKH + cc * 32 + g * 8);

  const int r_lo = lane >> 3;
  const int sgr = (lane & 7) ^ r_lo;

  auto STAGE = [&](int buf, int t64) {
#pragma unroll
    for (int j = 0; j < 2; ++j) {
      int row = w * 16 + j * 8 + r_lo;
      gld_lds16(Kp + (size_t)(t64 * 64 + row) * DKH + sgr * 8, &Ks[buf][(w * 2 + j) * 512]);
      gld_lds16(Vp + (size_t)row * SEQ + t64 * 64 + sgr * 8, &Vs[buf][(w * 2 + j) * 512]);
    }
  };

  STAGE(0, 0);
  STAGE(1, 1);
  asm volatile("s_waitcnt vmcnt(0)" ::: "memory");
  __builtin_amdgcn_s_barrier();

  f32x4 c[2][4] = {};
  float m_run[2] = {-1e30f, -1e30f}, l_run[2] = {0.f, 0.f};
  int cur = 0;

  for (int kt = 0; kt < nt; ++kt) {
    int b2 = cur + 2; if (b2 >= 3) b2 -= 3;
    if (kt + 2 < nt) STAGE(b2, kt + 2);   // prefetch distance 2

    f32x4 s[2][4] = {};
#pragma unroll
    for (int kn = 0; kn < 4; ++kn) {
      const char* krow = (const char*)&Ks[cur][(kn * 16 + lo) * 64];
#pragma unroll
      for (int cc = 0; cc < 2; ++cc) {
        bf16x8 ak = *(const bf16x8*)(krow + ((cc * 64 + g * 16) ^ swz));
        s[0][kn] = mfma16(ak, aq[0][cc], s[0][kn]);
        s[1][kn] = mfma16(ak, aq[1][cc], s[1][kn]);
      }
    }

    if (kt >= nt - 2) {  // diagonal region: mask key > q
#pragma unroll
      for (int qs = 0; qs < 2; ++qs) {
        int q = qmin + qs * 16 + lo;
#pragma unroll
        for (int kn = 0; kn < 4; ++kn)
#pragma unroll
          for (int i = 0; i < 4; ++i) {
            int key = kt * 64 + kn * 16 + g * 4 + i;
            if (key > q) s[qs][kn][i] = -1e30f;
          }
      }
    }

    bf16x8 pb[2][2];
#pragma unroll
    for (int qs = 0; qs < 2; ++qs) {
      float mx = s[qs][0][0];
#pragma unroll
      for (int kn = 0; kn < 4; ++kn)
#pragma unroll
        for (int i = 0; i < 4; ++i) mx = fmaxf(mx, s[qs][kn][i]);
      mx = fmaxf(mx, __shfl_xor(mx, 16));
      mx = fmaxf(mx, __shfl_xor(mx, 32));
      // T13 defer-rescale
      if (!__all(mx - m_run[qs] <= 8.0f)) {
        float mnew = fmaxf(m_run[qs], mx);
        float al = __builtin_amdgcn_exp2f(m_run[qs] - mnew);
        m_run[qs] = mnew;
        l_run[qs] *= al;
#pragma unroll
        for (int dn = 0; dn < 4; ++dn) {
          c[qs][dn][0] *= al; c[qs][dn][1] *= al;
          c[qs][dn][2] *= al; c[qs][dn][3] *= al;
        }
      }
      const float mq = m_run[qs];
      float rs = 0.f;
#pragma unroll
      for (int kn = 0; kn < 4; ++kn)
#pragma unroll
        for (int i = 0; i < 4; ++i) {
          float p = __builtin_amdgcn_exp2f(s[qs][kn][i] - mq);
          s[qs][kn][i] = p;
          rs += p;
        }
      rs += __shfl_xor(rs, 16);
      rs += __shfl_xor(rs, 32);
      l_run[qs] += rs;
#pragma unroll
      for (int kc = 0; kc < 2; ++kc) {
        bf16x8 t;
        t[0] = (short)f2bf_fast(s[qs][2 * kc][0]);
        t[1] = (short)f2bf_fast(s[qs][2 * kc][1]);
        t[2] = (short)f2bf_fast(s[qs][2 * kc][2]);
        t[3] = (short)f2bf_fast(s[qs][2 * kc][3]);
        t[4] = (short)f2bf_fast(s[qs][2 * kc + 1][0]);
        t[5] = (short)f2bf_fast(s[qs][2 * kc + 1][1]);
        t[6] = (short)f2bf_fast(s[qs][2 * kc + 1][2]);
        t[7] = (short)f2bf_fast(s[qs][2 * kc + 1][3]);
        pb[qs][kc] = t;
      }
    }

    // PV: O^T[d][q] += mfma(A = sigma-ordered V frag (single b128), B = P in-reg)
#pragma unroll
    for (int kc = 0; kc < 2; ++kc)
#pragma unroll
      for (int dn = 0; dn < 4; ++dn) {
        const char* vrow = (const char*)&Vs[cur][(dn * 16 + lo) * 64];
        bf16x8 av = *(const bf16x8*)(vrow + ((kc * 64 + g * 16) ^ swz));
        c[0][dn] = mfma16(av, pb[0][kc], c[0][dn]);
        c[1][dn] = mfma16(av, pb[1][kc], c[1][dn]);
      }

    if (kt + 1 < nt) {
      if (kt + 2 < nt) asm volatile("s_waitcnt vmcnt(4)" ::: "memory");
      else             asm volatile("s_waitcnt vmcnt(0)" ::: "memory");
      __builtin_amdgcn_s_barrier();
    }
    cur = (cur == 2) ? 0 : cur + 1;
  }

  // epilogue: O[q][d] = c/l
#pragma unroll
  for (int qs = 0; qs < 2; ++qs) {
    const float rl = 1.0f / l_run[qs];
    const int q = qmin + qs * 16 + lo;
#pragma unroll
    for (int dn = 0; dn < 4; ++dn) {
      ushort4 o;
      o.x = f2bf(c[qs][dn][0] * rl);
      o.y = f2bf(c[qs][dn][1] * rl);
      o.z = f2bf(c[qs][dn][2] * rl);
      o.w = f2bf(c[qs][dn][3] * rl);
      *(ushort4*)&ctx[((size_t)(b * SEQ + q)) * D_MODEL + h * DKH + dn * 16 + g * 4] = o;
    }
  }
}

extern "C" void kernel_launch(void* const* d_in, const int* in_sizes, int n_in,
                              void* d_out, int out_size, void* d_ws, size_t ws_size,
                              hipStream_t stream) {
  const float* q  = (const float*)d_in[0];
  const float* k  = (const float*)d_in[1];
  const float* v  = (const float*)d_in[2];
  // d_in[3] = attn_mask: fixed causal triu(k=1) -> hard-coded
  const float* Wq = (const float*)d_in[4];
  const float* bq = (const float*)d_in[5];
  const float* Wk = (const float*)d_in[6];
  const float* bk = (const float*)d_in[7];
  const float* Wv = (const float*)d_in[8];
  const float* bv = (const float*)d_in[9];
  const float* Wo = (const float*)d_in[10];
  const float* bo = (const float*)d_in[11];

  char* ws = (char*)d_ws;
  const size_t MB = 1u << 20;
  u16* ctxb = (u16*)(ws + 0 * MB);    // 16MB ctx
  u16* Wqkvt = (u16*)(ws + 48 * MB);  // [3072][1024]: Wq^T|Wk^T|Wv^T
  u16* Wot  = (u16*)(ws + 54 * MB);
  u16* Qhd  = (u16*)(ws + 56 * MB);
  u16* Khd  = (u16*)(ws + 72 * MB);
  u16* Vhd  = (u16*)(ws + 88 * MB);   // [B][H][64][SEQ], sigma-permuted keys

  u16* Wqt = Wqkvt;
  u16* Wkt = Wqkvt + 1024 * 1024;
  u16* Wvt = Wqkvt + 2 * 1024 * 1024;
  transpose_cvt4<<<dim3(32, 32, 4), dim3(32, 8), 0, stream>>>(
      Wq, Wk, Wv, Wo, Wqt, Wkt, Wvt, Wot);

  // Q scale folds 1/sqrt(dk) AND log2(e) for exp2-domain softmax
  const float qscale = 0.125f * 1.4426950408889634f;
  gemm_qkv_kernel<<<1536, 256, 0, stream>>>(q, k, v, Wqkvt,
                                            bq, bk, bv, Qhd, Khd, Vhd, qscale);

  attn_kernel<<<1024, 256, 0, stream>>>(Qhd, Khd, Vhd, ctxb);

  gemm_o_kernel<<<512, 256, 0, stream>>>(ctxb, Wot, bo, (float*)d_out);
}

// Round 14
// 170.284 us; speedup vs baseline: 1.1275x; 1.1275x over previous
//
#include <hip/hip_runtime.h>

#define D_MODEL 1024
#define NHEAD 16
#define DKH 64
#define BATCH 4
#define SEQ 2048
#define MROWS (BATCH*SEQ)   // 8192

typedef unsigned short u16;
typedef __attribute__((ext_vector_type(8))) short bf16x8;
typedef __attribute__((ext_vector_type(4))) float f32x4;

__device__ __forceinline__ u16 f2bf(float f) {
  union { float f; unsigned int u; } x; x.f = f;
  unsigned int r = x.u + 0x7FFFu + ((x.u >> 16) & 1u);
  return (u16)(r >> 16);
}
__device__ __forceinline__ u16 f2bf_fast(float f) {
  union { float f; unsigned int u; } x; x.f = f;
  return (u16)((x.u + 0x7FFFu) >> 16);
}

__device__ __forceinline__ f32x4 mfma16(bf16x8 a, bf16x8 b, f32x4 c) {
  return __builtin_amdgcn_mfma_f32_16x16x32_bf16(a, b, c, 0, 0, 0);
}

__device__ __forceinline__ void gld_lds16(const void* g, void* l) {
  __builtin_amdgcn_global_load_lds((const __attribute__((address_space(1))) unsigned int*)g,
                                   (__attribute__((address_space(3))) unsigned int*)l, 16, 0, 0);
}

// ---------------- fused prep: fp32->bf16 cvt (q,k,v) + 4x W transpose-cvt ----------------
// blocks [0, 24576): cvt (3 segments x 8192 blocks, 1024 elems/block)
// blocks [24576, 28672): transpose (4 matrices x 1024 tile-blocks of 32x32)
__global__ __launch_bounds__(256) void prep_kernel(
    const float* __restrict__ q, const float* __restrict__ k, const float* __restrict__ v,
    const float* __restrict__ W0, const float* __restrict__ W1,
    const float* __restrict__ W2, const float* __restrict__ W3,
    u16* __restrict__ oq, u16* __restrict__ ok, u16* __restrict__ ov,
    u16* __restrict__ T0, u16* __restrict__ T1,
    u16* __restrict__ T2, u16* __restrict__ T3) {
  const int blk = blockIdx.x;
  const int tid = threadIdx.x;
  if (blk < 24576) {
    const int seg = blk >> 13;            // /8192
    const int bi = blk & 8191;
    const float* in = (seg == 0) ? q : (seg == 1) ? k : v;
    u16* out = (seg == 0) ? oq : (seg == 1) ? ok : ov;
    int i = (bi * 256 + tid) * 4;
    float4 vv = *(const float4*)(in + i);
    ushort4 o;
    o.x = f2bf(vv.x); o.y = f2bf(vv.y); o.z = f2bf(vv.z); o.w = f2bf(vv.w);
    *(ushort4*)(out + i) = o;
  } else {
    __shared__ float tile[32][33];
    const int t = blk - 24576;
    const int z = t >> 10;                // matrix 0..3
    const int rem = t & 1023;
    const float* W = (z == 0) ? W0 : (z == 1) ? W1 : (z == 2) ? W2 : W3;
    u16* Wt = (z == 0) ? T0 : (z == 1) ? T1 : (z == 2) ? T2 : T3;
    const int bx = (rem & 31) * 32, by = (rem >> 5) * 32;
    const int tx = tid & 31, ty = tid >> 5;  // 32 x 8
#pragma unroll
    for (int j = 0; j < 32; j += 8)
      tile[ty + j][tx] = W[(size_t)(by + ty + j) * D_MODEL + bx + tx];
    __syncthreads();
#pragma unroll
    for (int j = 0; j < 32; j += 8)
      Wt[(size_t)(bx + ty + j) * D_MODEL + by + tx] = f2bf(tile[tx][ty + j]);
  }
}

// =====================================================================
// Pipelined 128x128 GEMM core (BK=64, 4 waves, derived counted-vmcnt).
// EXACT R8/R11 structure (proven 67us qkv, 0 conflicts, replay-safe).
// =====================================================================
template <typename Epi>
__device__ __forceinline__ void gemm_pipe(const u16* __restrict__ Ap,
                                          const u16* __restrict__ Bp,
                                          int m0, int n0g, Epi epi) {
  __shared__ u16 As[2][128 * 64];
  __shared__ u16 Bs[2][128 * 64];
  const int tid = threadIdx.x;
  const int lane = tid & 63;
  const int w = tid >> 6;
  const int wm = w >> 1, wn = w & 1;
  const int lo = lane & 15, g = lane >> 4;
  const int swz = (lo & 7) << 4;
  const int sg = (tid & 7) ^ ((tid >> 3) & 7);
  const int srow = tid >> 3;  // 0..31

  f32x4 acc[4][4] = {};

  auto STAGE_A = [&](int buf, int tt, int j) {
    int row = j * 32 + srow;
    gld_lds16(Ap + (size_t)(m0 + row) * D_MODEL + tt * 64 + sg * 8,
              &As[buf][j * 2048 + tid * 8]);
  };
  auto STAGE_B = [&](int buf, int tt, int j) {
    int row = j * 32 + srow;
    gld_lds16(Bp + (size_t)(n0g + row) * D_MODEL + tt * 64 + sg * 8,
              &Bs[buf][j * 2048 + tid * 8]);
  };

  STAGE_A(0, 0, 0); STAGE_A(0, 0, 1); STAGE_A(0, 0, 2); STAGE_A(0, 0, 3);
  STAGE_B(0, 0, 0); STAGE_B(0, 0, 1); STAGE_B(0, 0, 2); STAGE_B(0, 0, 3);
  STAGE_B(1, 1, 0); STAGE_B(1, 1, 1); STAGE_B(1, 1, 2); STAGE_B(1, 1, 3);
  asm volatile("s_waitcnt vmcnt(4)" ::: "memory");
  __builtin_amdgcn_s_barrier();

  int cur = 0;
#pragma unroll 1
  for (int t = 0; t < 16; ++t) {
    const int nb = cur ^ 1;
    const char* ab = (const char*)&As[cur][0];
    const char* bb2 = (const char*)&Bs[cur][0];

    // ---- P1: read B-frags + A-frags(m=0,1), stage A(t+1) ----
    bf16x8 bf[4][2], af[2][2];
#pragma unroll
    for (int n = 0; n < 4; ++n) {
      int row = wn * 64 + n * 16 + lo;
      bf[n][0] = *(const bf16x8*)(bb2 + row * 128 + ((g * 16) ^ swz));
      bf[n][1] = *(const bf16x8*)(bb2 + row * 128 + ((64 + g * 16) ^ swz));
    }
#pragma unroll
    for (int m = 0; m < 2; ++m) {
      int row = wm * 64 + m * 16 + lo;
      af[m][0] = *(const bf16x8*)(ab + row * 128 + ((g * 16) ^ swz));
      af[m][1] = *(const bf16x8*)(ab + row * 128 + ((64 + g * 16) ^ swz));
    }
    if (t + 1 < 16) {
      STAGE_A(nb, t + 1, 0); STAGE_A(nb, t + 1, 1);
      STAGE_A(nb, t + 1, 2); STAGE_A(nb, t + 1, 3);
    }
    __builtin_amdgcn_s_barrier();
    __builtin_amdgcn_s_setprio(1);
#pragma unroll
    for (int s2 = 0; s2 < 2; ++s2)
#pragma unroll
      for (int m = 0; m < 2; ++m)
#pragma unroll
        for (int n = 0; n < 4; ++n)
          acc[m][n] = mfma16(af[m][s2], bf[n][s2], acc[m][n]);
    __builtin_amdgcn_s_setprio(0);
    __builtin_amdgcn_s_barrier();

    // ---- P2: read A-frags(m=2,3), stage B(t+2) ----
    bf16x8 af2[2][2];
#pragma unroll
    for (int m = 0; m < 2; ++m) {
      int row = wm * 64 + (m + 2) * 16 + lo;
      af2[m][0] = *(const bf16x8*)(ab + row * 128 + ((g * 16) ^ swz));
      af2[m][1] = *(const bf16x8*)(ab + row * 128 + ((64 + g * 16) ^ swz));
    }
    if (t + 2 < 16) {
      STAGE_B(cur, t + 2, 0); STAGE_B(cur, t + 2, 1);
      STAGE_B(cur, t + 2, 2); STAGE_B(cur, t + 2, 3);
    }
    __builtin_amdgcn_s_barrier();
    __builtin_amdgcn_s_setprio(1);
#pragma unroll
    for (int s2 = 0; s2 < 2; ++s2)
#pragma unroll
      for (int m = 0; m < 2; ++m)
#pragma unroll
        for (int n = 0; n < 4; ++n)
          acc[m + 2][n] = mfma16(af2[m][s2], bf[n][s2], acc[m + 2][n]);
    __builtin_amdgcn_s_setprio(0);
    if (t + 2 < 16) asm volatile("s_waitcnt vmcnt(4)" ::: "memory");
    else            asm volatile("s_waitcnt vmcnt(0)" ::: "memory");
    __builtin_amdgcn_s_barrier();
    cur = nb;
  }

  epi(acc, wm, wn, lo, g);
}

// ---------------- fused QKV GEMM (chunk 0=Q,1=K,2=V; chunk uniform per block) ----------------
__global__ __launch_bounds__(256, 2) void gemm_qkv_kernel(
    const u16* __restrict__ Aq, const u16* __restrict__ Ak, const u16* __restrict__ Av,
    const u16* __restrict__ Wt,   // [3072][1024]
    const float* __restrict__ bq, const float* __restrict__ bk, const float* __restrict__ bv,
    u16* __restrict__ Qhd, u16* __restrict__ Khd, u16* __restrict__ Vhd, float qscale) {
  const int flat = blockIdx.x;
  const int swzb = (flat & 7) * 192 + (flat >> 3);
  const int m0 = (swzb / 24) * 128;
  const int n0g = (swzb % 24) * 128;
  const int chunk = n0g >> 10;  // block-uniform
  const u16* Ap = (chunk == 0) ? Aq : (chunk == 1) ? Ak : Av;
  const float* bias = (chunk == 0) ? bq : (chunk == 1) ? bk : bv;
  const float scale = (chunk == 0) ? qscale : 1.0f;

  gemm_pipe(Ap, Wt, m0, n0g,
    [&](f32x4 (&acc)[4][4], int wm, int wn, int lo, int g) {
#pragma unroll
      for (int m = 0; m < 4; ++m)
#pragma unroll
        for (int n = 0; n < 4; ++n) {
          int row0 = m0 + wm * 64 + m * 16 + g * 4;
          int colc = (n0g & 1023) + wn * 64 + n * 16 + lo;
          int hh = colc >> 6, d = colc & 63;
          int bb = row0 >> 11;
          float v0 = (acc[m][n][0] + bias[colc]) * scale;
          float v1 = (acc[m][n][1] + bias[colc]) * scale;
          float v2 = (acc[m][n][2] + bias[colc]) * scale;
          float v3 = (acc[m][n][3] + bias[colc]) * scale;
          if (chunk < 2) {
            u16* out = chunk ? Khd : Qhd;
#pragma unroll
            for (int i = 0; i < 4; ++i) {
              int l = (row0 + i) & 2047;
              float vi = (i == 0) ? v0 : (i == 1) ? v1 : (i == 2) ? v2 : v3;
              out[(((size_t)(bb * NHEAD + hh)) * SEQ + l) * DKH + d] = f2bf(vi);
            }
          } else {
            // V: transposed per head [B][H][64][SEQ], keys sigma-permuted within 32
            int l = row0 & 2047;
            int kh = (l >> 2) & 7;
            int pos = (l & ~31) | ((2 * (kh & 3) + (kh >> 2)) << 2);
            ushort4 o;
            o.x = f2bf(v0); o.y = f2bf(v1); o.z = f2bf(v2); o.w = f2bf(v3);
            *(ushort4*)&Vhd[(((size_t)(bb * NHEAD + hh)) * DKH + d) * SEQ + pos] = o;
          }
        }
    });
}

// ---------------- O GEMM: fp32 out ----------------
__global__ __launch_bounds__(256, 2) void gemm_o_kernel(
    const u16* __restrict__ A, const u16* __restrict__ Bt,
    const float* __restrict__ bias, float* __restrict__ Cout) {
  const int flat = blockIdx.x;           // 512 blocks
  const int swzb = (flat & 7) * 64 + (flat >> 3);
  const int m0 = (swzb >> 3) * 128;
  const int n0g = (swzb & 7) * 128;

  gemm_pipe(A, Bt, m0, n0g,
    [&](f32x4 (&acc)[4][4], int wm, int wn, int lo, int g) {
#pragma unroll
      for (int m = 0; m < 4; ++m)
#pragma unroll
        for (int n = 0; n < 4; ++n) {
          int row0 = m0 + wm * 64 + m * 16 + g * 4;
          int col = n0g + wn * 64 + n * 16 + lo;
          float bcol = bias[col];
#pragma unroll
          for (int i = 0; i < 4; ++i)
            Cout[(size_t)(row0 + i) * D_MODEL + col] = acc[m][n][i] + bcol;
        }
    });
}

// ---------------- causal flash attention (EXACT R11, replay-safe) ----------------
__global__ __launch_bounds__(256, 3) void attn_kernel(
    const u16* __restrict__ Qh, const u16* __restrict__ Kh,
    const u16* __restrict__ Vt, u16* __restrict__ ctx) {
  const int blk = blockIdx.x;             // 1024 blocks
  const int xcd = blk & 7;
  const int local = blk >> 3;             // 0..127
  const int qb = 15 - (local >> 3);       // LPT: biggest q-blocks first
  const int head = xcd * 8 + (local & 7); // head-XCD affinity
  const int b = head >> 4, h = head & (NHEAD - 1);

  const int tid = threadIdx.x;
  const int lane = tid & 63;
  const int w = tid >> 6;                 // 0..3
  const int lo = lane & 15, g = lane >> 4;
  const int swz = (lo & 7) << 4;

  __shared__ u16 Ks[3][64 * 64];
  __shared__ u16 Vs[3][64 * 64];

  const size_t hoff = ((size_t)(b * NHEAD + h)) * SEQ * DKH;
  const u16* Qp = Qh + hoff;
  const u16* Kp = Kh + hoff;
  const u16* Vp = Vt + hoff;       // [64][SEQ]

  const int nt = 2 * qb + 2;
  const int qmin = qb * 128 + w * 32;

  bf16x8 aq[2][2];
#pragma unroll
  for (int qs = 0; qs < 2; ++qs)
#pragma unroll
    for (int cc = 0; cc < 2; ++cc)
      aq[qs][cc] = *(const bf16x8*)(Qp + (size_t)(qmin + qs * 16 + lo) * DKH + cc * 32 + g * 8);

  const int r_lo = lane >> 3;
  const int sgr = (lane & 7) ^ r_lo;

  auto STAGE = [&](int buf, int t64) {
#pragma unroll
    for (int j = 0; j < 2; ++j) {
      int row = w * 16 + j * 8 + r_lo;
      gld_lds16(Kp + (size_t)(t64 * 64 + row) * DKH + sgr * 8, &Ks[buf][(w * 2 + j) * 512]);
      gld_lds16(Vp + (size_t)row * SEQ + t64 * 64 + sgr * 8, &Vs[buf][(w * 2 + j) * 512]);
    }
  };

  STAGE(0, 0);
  STAGE(1, 1);
  asm volatile("s_waitcnt vmcnt(0)" ::: "memory");
  __builtin_amdgcn_s_barrier();

  f32x4 c[2][4] = {};
  float m_run[2] = {-1e30f, -1e30f}, l_run[2] = {0.f, 0.f};
  int cur = 0;

  for (int kt = 0; kt < nt; ++kt) {
    int b2 = cur + 2; if (b2 >= 3) b2 -= 3;
    if (kt + 2 < nt) STAGE(b2, kt + 2);   // prefetch distance 2

    f32x4 s[2][4] = {};
#pragma unroll
    for (int kn = 0; kn < 4; ++kn) {
      const char* krow = (const char*)&Ks[cur][(kn * 16 + lo) * 64];
#pragma unroll
      for (int cc = 0; cc < 2; ++cc) {
        bf16x8 ak = *(const bf16x8*)(krow + ((cc * 64 + g * 16) ^ swz));
        s[0][kn] = mfma16(ak, aq[0][cc], s[0][kn]);
        s[1][kn] = mfma16(ak, aq[1][cc], s[1][kn]);
      }
    }

    if (kt >= nt - 2) {  // diagonal region: mask key > q
#pragma unroll
      for (int qs = 0; qs < 2; ++qs) {
        int q = qmin + qs * 16 + lo;
#pragma unroll
        for (int kn = 0; kn < 4; ++kn)
#pragma unroll
          for (int i = 0; i < 4; ++i) {
            int key = kt * 64 + kn * 16 + g * 4 + i;
            if (key > q) s[qs][kn][i] = -1e30f;
          }
      }
    }

    bf16x8 pb[2][2];
#pragma unroll
    for (int qs = 0; qs < 2; ++qs) {
      float mx = s[qs][0][0];
#pragma unroll
      for (int kn = 0; kn < 4; ++kn)
#pragma unroll
        for (int i = 0; i < 4; ++i) mx = fmaxf(mx, s[qs][kn][i]);
      mx = fmaxf(mx, __shfl_xor(mx, 16));
      mx = fmaxf(mx, __shfl_xor(mx, 32));
      // T13 defer-rescale
      if (!__all(mx - m_run[qs] <= 8.0f)) {
        float mnew = fmaxf(m_run[qs], mx);
        float al = __builtin_amdgcn_exp2f(m_run[qs] - mnew);
        m_run[qs] = mnew;
        l_run[qs] *= al;
#pragma unroll
        for (int dn = 0; dn < 4; ++dn) {
          c[qs][dn][0] *= al; c[qs][dn][1] *= al;
          c[qs][dn][2] *= al; c[qs][dn][3] *= al;
        }
      }
      const float mq = m_run[qs];
      float rs = 0.f;
#pragma unroll
      for (int kn = 0; kn < 4; ++kn)
#pragma unroll
        for (int i = 0; i < 4; ++i) {
          float p = __builtin_amdgcn_exp2f(s[qs][kn][i] - mq);
          s[qs][kn][i] = p;
          rs += p;
        }
      rs += __shfl_xor(rs, 16);
      rs += __shfl_xor(rs, 32);
      l_run[qs] += rs;
#pragma unroll
      for (int kc = 0; kc < 2; ++kc) {
        bf16x8 t;
        t[0] = (short)f2bf_fast(s[qs][2 * kc][0]);
        t[1] = (short)f2bf_fast(s[qs][2 * kc][1]);
        t[2] = (short)f2bf_fast(s[qs][2 * kc][2]);
        t[3] = (short)f2bf_fast(s[qs][2 * kc][3]);
        t[4] = (short)f2bf_fast(s[qs][2 * kc + 1][0]);
        t[5] = (short)f2bf_fast(s[qs][2 * kc + 1][1]);
        t[6] = (short)f2bf_fast(s[qs][2 * kc + 1][2]);
        t[7] = (short)f2bf_fast(s[qs][2 * kc + 1][3]);
        pb[qs][kc] = t;
      }
    }

    // PV: O^T[d][q] += mfma(A = sigma-ordered V frag (single b128), B = P in-reg)
#pragma unroll
    for (int kc = 0; kc < 2; ++kc)
#pragma unroll
      for (int dn = 0; dn < 4; ++dn) {
        const char* vrow = (const char*)&Vs[cur][(dn * 16 + lo) * 64];
        bf16x8 av = *(const bf16x8*)(vrow + ((kc * 64 + g * 16) ^ swz));
        c[0][dn] = mfma16(av, pb[0][kc], c[0][dn]);
        c[1][dn] = mfma16(av, pb[1][kc], c[1][dn]);
      }

    if (kt + 1 < nt) {
      if (kt + 2 < nt) asm volatile("s_waitcnt vmcnt(4)" ::: "memory");
      else             asm volatile("s_waitcnt vmcnt(0)" ::: "memory");
      __builtin_amdgcn_s_barrier();
    }
    cur = (cur == 2) ? 0 : cur + 1;
  }

  // epilogue: O[q][d] = c/l
#pragma unroll
  for (int qs = 0; qs < 2; ++qs) {
    const float rl = 1.0f / l_run[qs];
    const int q = qmin + qs * 16 + lo;
#pragma unroll
    for (int dn = 0; dn < 4; ++dn) {
      ushort4 o;
      o.x = f2bf(c[qs][dn][0] * rl);
      o.y = f2bf(c[qs][dn][1] * rl);
      o.z = f2bf(c[qs][dn][2] * rl);
      o.w = f2bf(c[qs][dn][3] * rl);
      *(ushort4*)&ctx[((size_t)(b * SEQ + q)) * D_MODEL + h * DKH + dn * 16 + g * 4] = o;
    }
  }
}

extern "C" void kernel_launch(void* const* d_in, const int* in_sizes, int n_in,
                              void* d_out, int out_size, void* d_ws, size_t ws_size,
                              hipStream_t stream) {
  const float* q  = (const float*)d_in[0];
  const float* k  = (const float*)d_in[1];
  const float* v  = (const float*)d_in[2];
  // d_in[3] = attn_mask: fixed causal triu(k=1) -> hard-coded
  const float* Wq = (const float*)d_in[4];
  const float* bq = (const float*)d_in[5];
  const float* Wk = (const float*)d_in[6];
  const float* bk = (const float*)d_in[7];
  const float* Wv = (const float*)d_in[8];
  const float* bv = (const float*)d_in[9];
  const float* Wo = (const float*)d_in[10];
  const float* bo = (const float*)d_in[11];

  char* ws = (char*)d_ws;
  const size_t MB = 1u << 20;
  u16* qb16 = (u16*)(ws + 0 * MB);    // reused as ctx later
  u16* kb16 = (u16*)(ws + 16 * MB);
  u16* vb16 = (u16*)(ws + 32 * MB);
  u16* Wqkvt = (u16*)(ws + 48 * MB);  // [3072][1024]: Wq^T|Wk^T|Wv^T
  u16* Wot  = (u16*)(ws + 54 * MB);
  u16* Qhd  = (u16*)(ws + 56 * MB);
  u16* Khd  = (u16*)(ws + 72 * MB);
  u16* Vhd  = (u16*)(ws + 88 * MB);   // [B][H][64][SEQ], sigma-permuted keys
  u16* ctxb = qb16;

  u16* Wqt = Wqkvt;
  u16* Wkt = Wqkvt + 1024 * 1024;
  u16* Wvt = Wqkvt + 2 * 1024 * 1024;

  // fused cvt + transpose: 24576 cvt blocks + 4096 transpose blocks
  prep_kernel<<<28672, 256, 0, stream>>>(q, k, v, Wq, Wk, Wv, Wo,
                                         qb16, kb16, vb16, Wqt, Wkt, Wvt, Wot);

  // Q scale folds 1/sqrt(dk) AND log2(e) for exp2-domain softmax
  const float qscale = 0.125f * 1.4426950408889634f;
  gemm_qkv_kernel<<<1536, 256, 0, stream>>>(qb16, kb16, vb16, Wqkvt,
                                            bq, bk, bv, Qhd, Khd, Vhd, qscale);

  attn_kernel<<<1024, 256, 0, stream>>>(Qhd, Khd, Vhd, ctxb);

  gemm_o_kernel<<<512, 256, 0, stream>>>(ctxb, Wot, bo, (float*)d_out);
}